// Round 5
// baseline (509.186 us; speedup 1.0000x reference)
//
#include <hip/hip_runtime.h>
#include <math.h>

#define VOCAB 32000
#define NB 16        // batch
#define NH 12        // heads
#define DEC_T 128
#define ALEN 512
#define DD 768
#define NT 512       // threads per block
#define NW 8         // waves per block
#define V4 8000      // VOCAB/4 float4 per row
#define CHUNKS 16    // ceil(V4/NT)
#define HSZ 1024     // hash slots (pow2, >= 2*ALEN -> load factor <= 0.5)
#define HMASK (HSZ - 1)
#define BMW (VOCAB / 32)   // 1000 bitmap words
#define HEMPTY 0xFFFFFFFFu

__device__ inline float wave_sum(float v) {
#pragma unroll
  for (int o = 32; o > 0; o >>= 1) v += __shfl_down(v, o, 64);
  return v;
}
__device__ inline float wave_max(float v) {
#pragma unroll
  for (int o = 32; o > 0; o >>= 1) v = fmaxf(v, __shfl_down(v, o, 64));
  return v;
}

__global__ __launch_bounds__(NT, 4) void pg_kernel(
    const float* __restrict__ dec, const float* __restrict__ fo,
    const float* __restrict__ attnw, const int* __restrict__ ids,
    const float* __restrict__ Wpg, const float* __restrict__ bpg,
    float* __restrict__ out) {
  // Scatter structures: 12.3 KB total (was 128 KB direct-mapped vocab array).
  // LDS 128KB -> 12.3KB is what unlocks 2 blocks/CU for cross-block overlap.
  __shared__ unsigned s_bm[BMW];     // presence bitmap, 4000 B
  __shared__ unsigned s_key[HSZ];    // hash keys, 4096 B
  __shared__ float    s_val[HSZ];    // hash values, 4096 B
  __shared__ float    s_red[NW];
  __shared__ float    s_res[8];

  const int bt = blockIdx.x;          // b*DEC_T + t
  const int b = bt / DEC_T;
  const int t = bt - b * DEC_T;
  const int tid = threadIdx.x;
  const int lane = tid & 63;
  const int wid = tid >> 6;

  // Issue full-row loads immediately. The first barrier still drains vmcnt(0),
  // but with 2 resident blocks/CU the other block covers the stall.
  const float4* row4 = (const float4*)(fo + (size_t)bt * VOCAB);
  float4 r[CHUNKS];
#pragma unroll
  for (int c = 0; c < CHUNKS; ++c) {
    int idx = c * NT + tid;           // only c==15 is conditional (tid<320)
    if (idx < V4) r[c] = row4[idx];
  }

  // zero bitmap + hash
  for (int i = tid; i < BMW; i += NT) s_bm[i] = 0u;
  for (int i = tid; i < HSZ; i += NT) { s_key[i] = HEMPTY; s_val[i] = 0.f; }

  // ---- p_gen = sigmoid(dec[bt,:] . Wpg + b) ----  (DD=768 = NT + 256)
  float pp = dec[(size_t)bt * DD + tid] * Wpg[tid];
  if (tid < DD - NT) pp += dec[(size_t)bt * DD + NT + tid] * Wpg[NT + tid];
  pp = wave_sum(pp);
  if (lane == 0) s_red[wid] = pp;
  __syncthreads();                    // also covers the zero loops above
  if (tid == 0) {
    float a = 0.f;
    for (int i = 0; i < NW; ++i) a += s_red[i];
    s_res[0] = a;
  }
  __syncthreads();
  const float pgen = 1.f / (1.f + __expf(-(s_res[0] + bpg[0])));

  // ---- attention: mean over heads, softmax over ALEN (ALEN == NT) ----
  const float* ap = attnw + ((size_t)b * NH * DEC_T + t) * ALEN + tid;
  float s = 0.f;
#pragma unroll
  for (int h = 0; h < NH; ++h) s += ap[(size_t)h * DEC_T * ALEN];
  const float amean = s * (1.f / NH);
  float am = wave_max(amean);
  if (lane == 0) s_red[wid] = am;
  __syncthreads();
  if (tid == 0) {
    float a = -INFINITY;
    for (int i = 0; i < NW; ++i) a = fmaxf(a, s_red[i]);
    s_res[1] = a;
  }
  __syncthreads();
  const float ae = __expf(amean - s_res[1]);
  float as = wave_sum(ae);
  if (lane == 0) s_red[wid] = as;
  __syncthreads();
  if (tid == 0) {
    float a = 0.f;
    for (int i = 0; i < NW; ++i) a += s_red[i];
    s_res[2] = a;
  }
  __syncthreads();
  const float ainv = (1.f - pgen) / s_res[2];

  // ---- scatter: bitmap bit + hash insert (duplicates merged by atomicAdd) ----
  {
    const float w = ae * ainv;
    const unsigned id = (unsigned)ids[b * ALEN + tid];
    atomicOr(&s_bm[id >> 5], 1u << (id & 31));
    unsigned h = (id * 2654435761u) >> 22;      // top 10 bits of Knuth hash
    for (;;) {
      unsigned old = atomicCAS(&s_key[h], HEMPTY, id);
      if (old == HEMPTY || old == id) { atomicAdd(&s_val[h], w); break; }
      h = (h + 1) & HMASK;                      // <=512 entries in 1024 slots
    }
  }

  // ---- vocab softmax: max ----
  float m = -INFINITY;
#pragma unroll
  for (int c = 0; c < CHUNKS; ++c) {
    int idx = c * NT + tid;
    if (idx < V4)
      m = fmaxf(m, fmaxf(fmaxf(r[c].x, r[c].y), fmaxf(r[c].z, r[c].w)));
  }
  m = wave_max(m);
  if (lane == 0) s_red[wid] = m;
  __syncthreads();                    // also publishes hash/bitmap writes
  if (tid == 0) {
    float a = -INFINITY;
    for (int i = 0; i < NW; ++i) a = fmaxf(a, s_red[i]);
    s_res[3] = a;
  }
  __syncthreads();
  const float fm = s_res[3];

  // ---- vocab softmax: denominator ----
  float zs = 0.f;
#pragma unroll
  for (int c = 0; c < CHUNKS; ++c) {
    int idx = c * NT + tid;
    if (idx < V4)
      zs += __expf(r[c].x - fm) + __expf(r[c].y - fm) +
            __expf(r[c].z - fm) + __expf(r[c].w - fm);
  }
  zs = wave_sum(zs);
  if (lane == 0) s_red[wid] = zs;
  __syncthreads();
  if (tid == 0) {
    float a = 0.f;
    for (int i = 0; i < NW; ++i) a += s_red[i];
    s_res[4] = a;
  }
  __syncthreads();
  const float Z = s_res[4];
  const float invZ = 1.f / Z;
  const float C = __logf(pgen) - fm - __logf(Z);

  auto hget = [&](unsigned id) -> float {
    unsigned h = (id * 2654435761u) >> 22;
    while (s_key[h] != id) h = (h + 1) & HMASK;  // bit set => present
    return s_val[h];
  };

  // ---- output: log(pgen*softmax + scatter) ----
  // scatter==0 (the common case, ~98.4%): x + C  (no exp/log, 1 bitmap word)
  float4* out4 = (float4*)(out + (size_t)bt * VOCAB);
#pragma unroll
  for (int c = 0; c < CHUNKS; ++c) {
    int idx = c * NT + tid;
    if (idx < V4) {
      const float4 x = r[c];
      float4 o;
      const unsigned nib = (s_bm[idx >> 3] >> ((idx & 7) * 4)) & 0xFu;
      if (nib == 0u) {
        o.x = x.x + C; o.y = x.y + C; o.z = x.z + C; o.w = x.w + C;
      } else {
        const unsigned v = (unsigned)idx * 4u;
        o.x = (nib & 1u) ? __logf(pgen * __expf(x.x - fm) * invZ + hget(v + 0u)) : (x.x + C);
        o.y = (nib & 2u) ? __logf(pgen * __expf(x.y - fm) * invZ + hget(v + 1u)) : (x.y + C);
        o.z = (nib & 4u) ? __logf(pgen * __expf(x.z - fm) * invZ + hget(v + 2u)) : (x.z + C);
        o.w = (nib & 8u) ? __logf(pgen * __expf(x.w - fm) * invZ + hget(v + 3u)) : (x.w + C);
      }
      out4[idx] = o;
    }
  }
}

extern "C" void kernel_launch(void* const* d_in, const int* in_sizes, int n_in,
                              void* d_out, int out_size, void* d_ws, size_t ws_size,
                              hipStream_t stream) {
  (void)in_sizes; (void)n_in; (void)out_size; (void)d_ws; (void)ws_size;
  const float* dec   = (const float*)d_in[0];   // (16,128,768)
  const float* fo    = (const float*)d_in[1];   // (16,128,32000)
  const float* attnw = (const float*)d_in[2];   // (16,12,128,512)
  const int*   ids   = (const int*)  d_in[3];   // (16,512)
  const float* Wpg   = (const float*)d_in[4];   // (768,1)
  const float* bpg   = (const float*)d_in[5];   // (1,)
  float* out = (float*)d_out;                   // (16,128,32000)

  pg_kernel<<<NB * DEC_T, NT, 0, stream>>>(dec, fo, attnw, ids, Wpg, bpg, out);
}